// Round 1
// baseline (6360.603 us; speedup 1.0000x reference)
//
#include <hip/hip_runtime.h>
#include <hip/hip_bf16.h>
#include <hip/hip_fp16.h>
#include <stdint.h>

// Seq2Seq LSTM: B=4096, H=512, E=128, 32 enc + 32 dec steps, V_tgt=128.
// Round 11: PERSISTENT CHAINS. R10 was ~23 us/step vs 4.1 us MFMA floor —
// the gap is per-launch overhead + cold staging + kernel-boundary L2 inv.
// The recurrence is independent per batch row, so replace 64 launches with
// 5 persistent launches (enc32, 4x dec8 + outproj) with per-m-tile arrival
// counters. 32 independent m-chains skew; spins hide under other chains.
// Coherence is fence-free: h-slot exchange uses relaxed AGENT-scope atomics
// only (execute at L3, bypass stale L1/L2), so W/proj stay L2-cached with
// no invalidation storm. c_state lives in registers for a whole launch.
// Slot layout [ctile][row][16] keeps writer fully coalesced (LDS bounce)
// and A-staging 16B chunks contiguous. Per-cell math identical to R10.

#define NB     4096
#define SSRC   32
#define STGT   32
#define NVSRC  96
#define NVTGT  128
#define ED     128
#define HD     512
#define G4     2048   // 4*HD
#define NBHD   ((size_t)NB * HD)

typedef __attribute__((ext_vector_type(8))) _Float16 half8;
typedef __attribute__((ext_vector_type(4))) float fx4;

#define AS_G __attribute__((address_space(1)))
#define AS_L __attribute__((address_space(3)))

__device__ __forceinline__ void gl2lds16(const void* g, void* l) {
    // async global->LDS DMA, 16B/lane; LDS dest = wave-uniform base + lane*16
    __builtin_amdgcn_global_load_lds((const AS_G uint32_t*)g, (AS_L uint32_t*)l, 16, 0, 0);
}

__device__ __forceinline__ float sigf(float x) { return 1.0f / (1.0f + __expf(-x)); }
__device__ __forceinline__ float tanhfast(float x) { return 1.0f - 2.0f / (__expf(2.0f * x) + 1.0f); }

__global__ void convert_half(const float* __restrict__ src, int n, _Float16* __restrict__ dst) {
    int i = blockIdx.x * 256 + threadIdx.x;
    if (i < n) dst[i] = (_Float16)src[i];
}

// 32x32 LDS-tiled transpose: outT[c][r] = in[r][c]; both sides coalesced.
__global__ __launch_bounds__(256) void transpose_f32(
    const float* __restrict__ in, float* __restrict__ outT, int R, int C, int rtiles)
{
    __shared__ float ls[32][33];
    const int bx = (int)blockIdx.x % rtiles;     // r-tile
    const int by = (int)blockIdx.x / rtiles;     // c-tile
    const int tx = threadIdx.x & 31, ty = threadIdx.x >> 5;   // ty 0..7
    #pragma unroll
    for (int i = 0; i < 4; i++) {
        int rr = ty + i * 8;
        ls[rr][tx] = in[(size_t)(bx * 32 + rr) * C + by * 32 + tx];
    }
    __syncthreads();
    #pragma unroll
    for (int i = 0; i < 4; i++) {
        int rr = ty + i * 8;
        outT[(size_t)(by * 32 + rr) * R + bx * 32 + tx] = ls[tx][rr];
    }
}

// proj[v][g] = emb[v,:]·Wih[g,:] + bih[g] + bhh[g], using WT[e][g] (coalesced).
__global__ __launch_bounds__(256) void build_tables3(
    const float* __restrict__ emb, const float* __restrict__ WT,
    const float* __restrict__ bih, const float* __restrict__ bhh,
    float* __restrict__ proj)
{
    __shared__ float embL[8][ED];
    const int gc = (int)blockIdx.x & 7;
    const int vc = (int)blockIdx.x >> 3;
    const int g  = gc * 256 + threadIdx.x;
    for (int i = threadIdx.x; i < 8 * ED; i += 256)
        embL[i >> 7][i & (ED - 1)] = emb[(size_t)(vc * 8 + (i >> 7)) * ED + (i & (ED - 1))];
    __syncthreads();
    float acc[8] = {0, 0, 0, 0, 0, 0, 0, 0};
    for (int e = 0; e < ED; e++) {
        float w = WT[(size_t)e * G4 + g];
        #pragma unroll
        for (int v = 0; v < 8; v++) acc[v] += embL[v][e] * w;
    }
    float bb = bih[g] + bhh[g];
    #pragma unroll
    for (int v = 0; v < 8; v++)
        proj[(size_t)(vc * 8 + v) * G4 + g] = acc[v] + bb;
}

// Persistent multi-step LSTM. 1024 blocks = 4/CU (guaranteed co-resident by
// launch_bounds(256,4) + 24KB LDS). Gate GEMM 128m x 64n per block + fused
// cell epilogue, identical math/order to R10's lstm_step.
// h slots layout: [ctile 32][row 4096][c 16] fp16 — exchanged ONLY via
// relaxed agent-scope atomics (coherent at L3). W/proj/seq via normal
// (L2-cached) loads; no fences, no cache invalidation anywhere.
template <int IS_ENC>
__global__ __launch_bounds__(256, 4) void lstm_persist(
    _Float16* __restrict__ slots, float* __restrict__ c_state,
    const float* __restrict__ proj,
    const int* __restrict__ seq, const int* __restrict__ lens,
    const _Float16* __restrict__ W,
    unsigned int* __restrict__ cnt,   // [64][32] arrival counters
    int t0, int nsteps)
{
    __shared__ __align__(16) _Float16 lsA[128 * 64];   // 16 KB
    __shared__ __align__(16) _Float16 lsB[64 * 64];    // 8 KB (also h bounce)

    const int tid = threadIdx.x;
    const int lane = tid & 63;
    const int wid  = tid >> 6;
    const int srow = lane >> 3;                    // staging row-in-group
    const int skc  = (((lane & 7) ^ srow)) << 3;   // XOR-swizzled k-chunk
    const int wm   = wid * 32;                     // wave m-offset (0..96)
    const int quad = lane >> 4;
    const int l15  = lane & 15;

    // block -> (m-tile, c-tile): XCD-partitioned; CU-skewed so a CU's 4
    // resident blocks belong to 4 DIFFERENT m-chains (spin overlap).
    const int x = (int)blockIdx.x & 7, j = (int)blockIdx.x >> 3;
    const int mt = (x & 1) * 16 + (((j & 15) + ((j >> 5) << 2)) & 15);
    const int m0 = mt * 128;
    const int ct = (x >> 1) * 8 + (j >> 4);        // c-tile 0..31
    const int c0 = ct * 16;
    const int hcol = c0 + l15;

    // A-staging source offsets (elements within a slot, [ct][row][16] layout)
    int aoff[4];
    #pragma unroll
    for (int i = 0; i < 4; i++) {
        int lr = wid * 32 + i * 8 + srow;          // local A row 0..127
        aoff[i] = ((skc >> 4) * NB + (m0 + lr)) * 16 + (skc & 8);
    }
    // B source: W[4H][HD], row = gate*HD + hcol
    const _Float16* bg[2];
    #pragma unroll
    for (int i = 0; i < 2; i++) {
        int lr = wid * 16 + i * 8 + srow;          // local B row 0..63
        int wr = (lr >> 4) * HD + c0 + (lr & 15);
        bg[i] = W + (size_t)wr * HD + skc;
    }

    // persistent per-lane cell state: 8 cells at (row(mf,r), hcol)
    float creg[2][4];
    _Float16 hreg[2][4];
    int lenreg[2][4];
    #pragma unroll
    for (int mf = 0; mf < 2; mf++)
        #pragma unroll
        for (int r = 0; r < 4; r++) {
            int row = m0 + wm + mf * 16 + quad * 4 + r;
            creg[mf][r] = c_state[(size_t)row * HD + hcol];
            hreg[mf][r] = (_Float16)0.0f;
            if (IS_ENC) lenreg[mf][r] = lens[row];
        }

    for (int s = 0; s < nsteps; s++) {
        const int t = t0 + s;
        const _Float16* h_r;
        _Float16* h_w;
        if (IS_ENC) {
            h_r = slots + (size_t)(10 + (t & 1)) * NBHD;
            h_w = slots + (size_t)(10 + ((t + 1) & 1)) * NBHD;
        } else {
            h_r = slots + (size_t)((t == 0) ? 10 : ((t - 1) % 10)) * NBHD;
            h_w = slots + (size_t)(t % 10) * NBHD;
        }

        // ---- wait: all 32 same-m blocks finished step t-1 (launch-first
        // step needs no wait: previous launch ordered by the stream).
        if (s > 0) {
            if (tid == 0) {
                const unsigned int* f =
                    cnt + (size_t)((IS_ENC ? t : 32 + t) - 1) * 32 + mt;
                while (__hip_atomic_load(f, __ATOMIC_RELAXED,
                                         __HIP_MEMORY_SCOPE_AGENT) < 32u)
                    __builtin_amdgcn_s_sleep(1);
            }
            __syncthreads();
            asm volatile("" ::: "memory");   // keep h loads below the spin
        }

        fx4 acc[2][4];
        #pragma unroll
        for (int i = 0; i < 2; i++)
            #pragma unroll
            for (int jj = 0; jj < 4; jj++)
                acc[i][jj] = fx4{0.f, 0.f, 0.f, 0.f};

        if (!(IS_ENC && t == 0)) {           // enc s=0: h==0, skip GEMM
            for (int k0 = 0; k0 < HD; k0 += 64) {
                const size_t kt = (size_t)(k0 >> 4) * (NB * 16);
                // A: coherent (agent-atomic, L3) loads to regs — issued
                // before the barrier so L3 latency overlaps the wait.
                unsigned long long av[4][2];
                #pragma unroll
                for (int i = 0; i < 4; i++) {
                    const unsigned long long* p =
                        (const unsigned long long*)(h_r + kt + aoff[i]);
                    av[i][0] = __hip_atomic_load(p, __ATOMIC_RELAXED,
                                                 __HIP_MEMORY_SCOPE_AGENT);
                    av[i][1] = __hip_atomic_load(p + 1, __ATOMIC_RELAXED,
                                                 __HIP_MEMORY_SCOPE_AGENT);
                }
                __syncthreads();             // prev iter's LDS reads done
                #pragma unroll
                for (int i = 0; i < 2; i++)  // B: normal path, L2-cached
                    gl2lds16(bg[i] + k0, &lsB[(wid * 16 + i * 8) * 64]);
                #pragma unroll
                for (int i = 0; i < 4; i++) {
                    unsigned long long* d = (unsigned long long*)
                        &lsA[(wid * 32 + i * 8) * 64 + lane * 8];
                    d[0] = av[i][0];
                    d[1] = av[i][1];
                }
                __syncthreads();
                #pragma unroll
                for (int kk = 0; kk < 64; kk += 32) {
                    const int kc = (kk >> 3) + quad;
                    half8 af[2], bf[4];
                    #pragma unroll
                    for (int mf = 0; mf < 2; mf++) {
                        int ar = wm + mf * 16 + l15;
                        int sw = ((kc ^ (ar & 7)) << 3);
                        af[mf] = *(const half8*)&lsA[ar * 64 + sw];
                    }
                    #pragma unroll
                    for (int g = 0; g < 4; g++) {
                        int br = g * 16 + l15;
                        int sw = ((kc ^ (br & 7)) << 3);
                        bf[g] = *(const half8*)&lsB[br * 64 + sw];
                    }
                    #pragma unroll
                    for (int mf = 0; mf < 2; mf++)
                        #pragma unroll
                        for (int g = 0; g < 4; g++)
                            acc[mf][g] = __builtin_amdgcn_mfma_f32_16x16x32_f16(
                                af[mf], bf[g], acc[mf][g], 0, 0, 0);
                }
            }
        }

        // ---- fused cell epilogue (identical math to R10), h via LDS bounce
        __syncthreads();                      // lsB frag reads done
        _Float16* htile = lsB;                // [128][16]
        #pragma unroll
        for (int mf = 0; mf < 2; mf++) {
            #pragma unroll
            for (int r = 0; r < 4; r++) {
                const int lrow = wm + mf * 16 + quad * 4 + r;
                const int row = m0 + lrow;
                int tok;
                if (IS_ENC) tok = seq[row * SSRC + t];
                else        tok = (t == 0) ? 1 : seq[row * STGT + t - 1]; // SOS=1
                const float* xp = proj + (size_t)tok * G4 + hcol;
                float gi = acc[mf][0][r] + xp[0];
                float gf = acc[mf][1][r] + xp[HD];
                float gg = acc[mf][2][r] + xp[2 * HD];
                float go = acc[mf][3][r] + xp[3 * HD];
                float ii = sigf(gi), ff = sigf(gf), oo = sigf(go);
                float g2 = tanhfast(gg);
                float cold = creg[mf][r];
                float c2 = ff * cold + ii * g2;
                _Float16 h2 = (_Float16)(oo * tanhfast(c2));
                if (IS_ENC && t >= lenreg[mf][r]) {   // pack_padded semantics
                    c2 = cold;
                    h2 = hreg[mf][r];                  // exact fp16 carry
                }
                creg[mf][r] = c2;
                if (IS_ENC) hreg[mf][r] = h2;
                htile[lrow * 16 + l15] = h2;
            }
        }
        __syncthreads();
        {   // coalesced write-through (agent-atomic -> L3): 16B/thread
            const int lrow = tid >> 1, cof = (tid & 1) * 8;
            const unsigned long long* sv =
                (const unsigned long long*)&htile[lrow * 16 + cof];
            unsigned long long v0 = sv[0], v1 = sv[1];
            unsigned long long* dp = (unsigned long long*)
                (h_w + ((size_t)ct * NB + (m0 + lrow)) * 16 + cof);
            __hip_atomic_store(dp, v0, __ATOMIC_RELAXED, __HIP_MEMORY_SCOPE_AGENT);
            __hip_atomic_store(dp + 1, v1, __ATOMIC_RELAXED, __HIP_MEMORY_SCOPE_AGENT);
        }
        // ---- arrive: barrier drains vmcnt(0) => stores committed at L3
        if (s < nsteps - 1) {
            asm volatile("" ::: "memory");
            __syncthreads();
            if (tid == 0)
                __hip_atomic_fetch_add(
                    cnt + (size_t)(IS_ENC ? t : 32 + t) * 32 + mt, 1u,
                    __ATOMIC_RELAXED, __HIP_MEMORY_SCOPE_AGENT);
        }
    }

    #pragma unroll
    for (int mf = 0; mf < 2; mf++)
        #pragma unroll
        for (int r = 0; r < 4; r++) {
            int row = m0 + wm + mf * 16 + quad * 4 + r;
            c_state[(size_t)row * HD + hcol] = creg[mf][r];
        }
}

// Batched outproj: 256 blocks = (8 t) x (32 m-tiles), each 128x128x512.
// A-addressing updated for the [ctile][row][16] slot layout.
__global__ __launch_bounds__(256, 2) void outproj_batch(
    const _Float16* __restrict__ h_slots, int t0,
    const _Float16* __restrict__ Wo, const float* __restrict__ bout,
    float* __restrict__ out)
{
    __shared__ __align__(16) _Float16 lsA[128 * 64];
    __shared__ __align__(16) _Float16 lsB[128 * 64];

    const int tid = threadIdx.x;
    const int lane = tid & 63;
    const int wid  = tid >> 6;
    const int srow = lane >> 3;
    const int skc  = (((lane & 7) ^ srow)) << 3;
    const int wm    = (wid >> 1) * 64;
    const int wncol = wid & 1;
    const int quad  = lane >> 4;
    const int l15   = lane & 15;
    const int bsw   = (l15 & 7);

    const int t  = t0 + ((int)blockIdx.x >> 5);
    const int m0 = ((int)blockIdx.x & 31) * 128;
    const _Float16* h_r = h_slots + (size_t)(t % 10) * NBHD;

    int aoff[4];
    const _Float16* bg[4];
    #pragma unroll
    for (int i = 0; i < 4; i++) {
        int lr = wid * 32 + i * 8 + srow;
        aoff[i] = ((skc >> 4) * NB + (m0 + lr)) * 16 + (skc & 8);
        bg[i] = Wo + (size_t)lr * HD + skc;   // Wout row = v
    }

    fx4 acc[4][4];
    #pragma unroll
    for (int i = 0; i < 4; i++)
        #pragma unroll
        for (int jj = 0; jj < 4; jj++)
            acc[i][jj] = fx4{0.f, 0.f, 0.f, 0.f};

    for (int k0 = 0; k0 < HD; k0 += 64) {
        const size_t kt = (size_t)(k0 >> 4) * (NB * 16);
        __syncthreads();
        #pragma unroll
        for (int i = 0; i < 4; i++) {
            int lb = (wid * 32 + i * 8) * 64;
            gl2lds16(h_r + kt + aoff[i], &lsA[lb]);
            gl2lds16(bg[i] + k0, &lsB[lb]);
        }
        __syncthreads();
        #pragma unroll
        for (int kk = 0; kk < 64; kk += 32) {
            const int kc = (kk >> 3) + quad;
            const int sw = ((kc ^ bsw) << 3);
            half8 af[4], bf[4];
            #pragma unroll
            for (int mt = 0; mt < 4; mt++)
                af[mt] = *(const half8*)&lsA[(wm + mt * 16 + l15) * 64 + sw];
            #pragma unroll
            for (int nt = 0; nt < 4; nt++)
                bf[nt] = *(const half8*)&lsB[(wncol * 64 + nt * 16 + l15) * 64 + sw];
            #pragma unroll
            for (int mt = 0; mt < 4; mt++)
                #pragma unroll
                for (int nt = 0; nt < 4; nt++)
                    acc[mt][nt] = __builtin_amdgcn_mfma_f32_16x16x32_f16(af[mt], bf[nt], acc[mt][nt], 0, 0, 0);
        }
    }

    #pragma unroll
    for (int mt = 0; mt < 4; mt++)
        #pragma unroll
        for (int nt = 0; nt < 4; nt++) {
            int v = wncol * 64 + nt * 16 + l15;
            float bo = bout[v];
            #pragma unroll
            for (int r = 0; r < 4; r++) {
                int row = m0 + wm + mt * 16 + quad * 4 + r;
                out[((size_t)row * STGT + t) * NVTGT + v] = acc[mt][nt][r] + bo;
            }
        }
}

extern "C" void kernel_launch(void* const* d_in, const int* in_sizes, int n_in,
                              void* d_out, int out_size, void* d_ws, size_t ws_size,
                              hipStream_t stream) {
    (void)in_sizes; (void)n_in; (void)out_size; (void)ws_size;
    const int* src_seq = (const int*)d_in[0];
    const int* src_len = (const int*)d_in[1];
    const int* tgt_seq = (const int*)d_in[2];
    const float* emb_src = (const float*)d_in[3];
    const float* eWih = (const float*)d_in[4];
    const float* eWhh = (const float*)d_in[5];
    const float* ebih = (const float*)d_in[6];
    const float* ebhh = (const float*)d_in[7];
    const float* emb_tgt = (const float*)d_in[8];
    const float* dWih = (const float*)d_in[9];
    const float* dWhh = (const float*)d_in[10];
    const float* dbih = (const float*)d_in[11];
    const float* dbhh = (const float*)d_in[12];
    const float* Wout = (const float*)d_in[13];
    const float* bout = (const float*)d_in[14];
    float* out = (float*)d_out;

    char* ws = (char*)d_ws;
    size_t off = 0;
    auto carve = [&](size_t bytes) { void* p = ws + off; off += (bytes + 255) & ~(size_t)255; return p; };
    float* proj_src = (float*)carve((size_t)NVSRC * G4 * 4);
    float* proj_tgt = (float*)carve((size_t)NVTGT * G4 * 4);
    float* c_state  = (float*)carve(NBHD * 4);
    _Float16* slots = (_Float16*)carve((size_t)12 * NBHD * 2);   // 48 MB
    _Float16* eW_h  = (_Float16*)carve((size_t)G4 * HD * 2);
    _Float16* dW_h  = (_Float16*)carve((size_t)G4 * HD * 2);
    _Float16* Wo_h  = (_Float16*)carve((size_t)NVTGT * HD * 2);
    unsigned int* cnt = (unsigned int*)carve((size_t)64 * 32 * 4); // arrivals
    // WT buffers alias decoder slot 0 (first written at decoder step 0,
    // long after tables are built). 1 MB each, slot is 4 MB.
    float* WT_e = (float*)(slots);
    float* WT_d = (float*)((char*)slots + (size_t)ED * G4 * 4);

    hipMemsetAsync(c_state, 0, NBHD * 4, stream);
    hipMemsetAsync(cnt, 0, (size_t)64 * 32 * 4, stream);

    convert_half<<<dim3(G4 * HD / 256), dim3(256), 0, stream>>>(eWhh, G4 * HD, eW_h);
    convert_half<<<dim3(G4 * HD / 256), dim3(256), 0, stream>>>(dWhh, G4 * HD, dW_h);
    convert_half<<<dim3(NVTGT * HD / 256), dim3(256), 0, stream>>>(Wout, NVTGT * HD, Wo_h);
    transpose_f32<<<dim3((G4 / 32) * (ED / 32)), dim3(256), 0, stream>>>(eWih, WT_e, G4, ED, G4 / 32);
    transpose_f32<<<dim3((G4 / 32) * (ED / 32)), dim3(256), 0, stream>>>(dWih, WT_d, G4, ED, G4 / 32);
    build_tables3<<<dim3((NVSRC / 8) * 8), dim3(256), 0, stream>>>(emb_src, WT_e, ebih, ebhh, proj_src);
    build_tables3<<<dim3((NVTGT / 8) * 8), dim3(256), 0, stream>>>(emb_tgt, WT_d, dbih, dbhh, proj_tgt);

    // encoder: one persistent launch, 32 steps (slots 10/11 alternate)
    lstm_persist<1><<<dim3(1024), dim3(256), 0, stream>>>(
        slots, c_state, proj_src, src_seq, src_len, eW_h, cnt, 0, 32);
    // decoder: 4 persistent launches of 8 steps (ring-10), outproj between
    for (int k = 0; k < 4; k++) {
        lstm_persist<0><<<dim3(1024), dim3(256), 0, stream>>>(
            slots, c_state, proj_tgt, tgt_seq, nullptr, dW_h, cnt, k * 8, 8);
        outproj_batch<<<dim3(256), dim3(256), 0, stream>>>(
            slots, k * 8, Wo_h, bout, out);
    }
}

// Round 2
// 3562.432 us; speedup vs baseline: 1.7855x; 1.7855x over previous
//
#include <hip/hip_runtime.h>
#include <hip/hip_bf16.h>
#include <hip/hip_fp16.h>
#include <stdint.h>

// Seq2Seq LSTM: B=4096, H=512, E=128, 32 enc + 32 dec steps, V_tgt=128.
// Round 12: XCD-LOCAL PERSISTENT CHAINS. R11 failed (6.4 ms) because ALL h
// traffic went through agent-scope atomics = uncached 8B fabric transactions
// (MfmaUtil 3.2%, 767 MB HBM fetch/launch). Fix: keep persistence, but pin
// each m-chain's 32 blocks to ONE XCD (dispatch round-robins XCDs, bid&7).
// h exchange then stays inside that XCD's shared L2:
//   producer: LDS bounce -> normal 16B stores (write-through to L2) ->
//             per-thread vmcnt(0) -> barrier -> tid0 agent-atomic signal
//   consumer: spin on agent-atomic counter -> stage A with
//             global_load_dwordx4 sc0 (L1-bypass, L2-hit = fresh) + ds_write
// W/proj/seq are immutable -> keep global_load_lds + normal caching.
// CU-skew: 4 different chains per CU so spins hide under other chains' MFMA.
// Per-cell math identical to R10/R11 -> absmax unchanged.

#define NB     4096
#define SSRC   32
#define STGT   32
#define NVSRC  96
#define NVTGT  128
#define ED     128
#define HD     512
#define G4     2048   // 4*HD
#define NBHD   ((size_t)NB * HD)

typedef __attribute__((ext_vector_type(8))) _Float16 half8;
typedef __attribute__((ext_vector_type(4))) float fx4;
typedef __attribute__((ext_vector_type(4))) int intx4;

#define AS_G __attribute__((address_space(1)))
#define AS_L __attribute__((address_space(3)))

__device__ __forceinline__ void gl2lds16(const void* g, void* l) {
    // async global->LDS DMA, 16B/lane; LDS dest = wave-uniform base + lane*16
    __builtin_amdgcn_global_load_lds((const AS_G uint32_t*)g, (AS_L uint32_t*)l, 16, 0, 0);
}

__device__ __forceinline__ float sigf(float x) { return 1.0f / (1.0f + __expf(-x)); }
__device__ __forceinline__ float tanhfast(float x) { return 1.0f - 2.0f / (__expf(2.0f * x) + 1.0f); }

__global__ void convert_half(const float* __restrict__ src, int n, _Float16* __restrict__ dst) {
    int i = blockIdx.x * 256 + threadIdx.x;
    if (i < n) dst[i] = (_Float16)src[i];
}

// 32x32 LDS-tiled transpose: outT[c][r] = in[r][c]; both sides coalesced.
__global__ __launch_bounds__(256) void transpose_f32(
    const float* __restrict__ in, float* __restrict__ outT, int R, int C, int rtiles)
{
    __shared__ float ls[32][33];
    const int bx = (int)blockIdx.x % rtiles;     // r-tile
    const int by = (int)blockIdx.x / rtiles;     // c-tile
    const int tx = threadIdx.x & 31, ty = threadIdx.x >> 5;   // ty 0..7
    #pragma unroll
    for (int i = 0; i < 4; i++) {
        int rr = ty + i * 8;
        ls[rr][tx] = in[(size_t)(bx * 32 + rr) * C + by * 32 + tx];
    }
    __syncthreads();
    #pragma unroll
    for (int i = 0; i < 4; i++) {
        int rr = ty + i * 8;
        outT[(size_t)(by * 32 + rr) * R + bx * 32 + tx] = ls[tx][rr];
    }
}

// proj[v][g] = emb[v,:]·Wih[g,:] + bih[g] + bhh[g], using WT[e][g] (coalesced).
__global__ __launch_bounds__(256) void build_tables3(
    const float* __restrict__ emb, const float* __restrict__ WT,
    const float* __restrict__ bih, const float* __restrict__ bhh,
    float* __restrict__ proj)
{
    __shared__ float embL[8][ED];
    const int gc = (int)blockIdx.x & 7;
    const int vc = (int)blockIdx.x >> 3;
    const int g  = gc * 256 + threadIdx.x;
    for (int i = threadIdx.x; i < 8 * ED; i += 256)
        embL[i >> 7][i & (ED - 1)] = emb[(size_t)(vc * 8 + (i >> 7)) * ED + (i & (ED - 1))];
    __syncthreads();
    float acc[8] = {0, 0, 0, 0, 0, 0, 0, 0};
    for (int e = 0; e < ED; e++) {
        float w = WT[(size_t)e * G4 + g];
        #pragma unroll
        for (int v = 0; v < 8; v++) acc[v] += embL[v][e] * w;
    }
    float bb = bih[g] + bhh[g];
    #pragma unroll
    for (int v = 0; v < 8; v++)
        proj[(size_t)(vc * 8 + v) * G4 + g] = acc[v] + bb;
}

// Persistent multi-step LSTM. 1024 blocks = exactly 4/CU (launch_bounds(256,4)
// + 24KB LDS => all co-resident). Gate GEMM 128m x 64n per block + fused cell
// epilogue, identical math/order to R10.
// h slots layout: [ctile 32][row 4096][c 16] fp16. Chain = m-tile; all 32
// ct-blocks of a chain sit on ONE XCD (bid&7), so h stays in that XCD's L2.
template <int IS_ENC>
__global__ __launch_bounds__(256, 4) void lstm_persist(
    _Float16* __restrict__ slots, float* __restrict__ c_state,
    const float* __restrict__ proj,
    const int* __restrict__ seq, const int* __restrict__ lens,
    const _Float16* __restrict__ W,
    unsigned int* __restrict__ cnt,   // [64][32] arrival counters
    int t0, int nsteps)
{
    __shared__ __align__(16) _Float16 lsA[128 * 64];   // 16 KB
    __shared__ __align__(16) _Float16 lsB[64 * 64];    // 8 KB (also h bounce)

    const int tid = threadIdx.x;
    const int lane = tid & 63;
    const int wid  = tid >> 6;
    const int srow = lane >> 3;                    // staging row-in-group
    const int skc  = (((lane & 7) ^ srow)) << 3;   // XOR-swizzled k-chunk
    const int wm   = wid * 32;                     // wave m-offset (0..96)
    const int quad = lane >> 4;
    const int l15  = lane & 15;

    // XCD-local chain mapping: xcd = bid&7 hosts chains xcd*4 .. xcd*4+3.
    // (r+w)&3 spreads a CU's 4 resident blocks across 4 different chains
    // under either CU-fill order (stride-32 or consecutive).
    const int x = (int)blockIdx.x & 7;
    const int k = (int)blockIdx.x >> 3;            // 0..127 within XCD
    const int w = k >> 5, r = k & 31;
    const int mt = x * 4 + ((r + w) & 3);          // chain / m-tile 0..31
    const int m0 = mt * 128;
    const int ct = w * 8 + (r >> 2);               // c-tile 0..31
    const int c0 = ct * 16;
    const int hcol = c0 + l15;

    // A-staging source offsets (elements within a slot, [ct][row][16] layout)
    int aoff[4];
    #pragma unroll
    for (int i = 0; i < 4; i++) {
        int lr = wid * 32 + i * 8 + srow;          // local A row 0..127
        aoff[i] = ((skc >> 4) * NB + (m0 + lr)) * 16 + (skc & 8);
    }
    // B source: W[4H][HD], row = gate*HD + hcol
    const _Float16* bg[2];
    #pragma unroll
    for (int i = 0; i < 2; i++) {
        int lr = wid * 16 + i * 8 + srow;          // local B row 0..63
        int wr = (lr >> 4) * HD + c0 + (lr & 15);
        bg[i] = W + (size_t)wr * HD + skc;
    }

    // persistent per-lane cell state: 8 cells at (row(mf,r), hcol)
    float creg[2][4];
    _Float16 hreg[2][4];
    int lenreg[2][4];
    #pragma unroll
    for (int mf = 0; mf < 2; mf++)
        #pragma unroll
        for (int rr = 0; rr < 4; rr++) {
            int row = m0 + wm + mf * 16 + quad * 4 + rr;
            creg[mf][rr] = c_state[(size_t)row * HD + hcol];
            hreg[mf][rr] = (_Float16)0.0f;
            if (IS_ENC) lenreg[mf][rr] = lens[row];
        }

    for (int s = 0; s < nsteps; s++) {
        const int t = t0 + s;
        const _Float16* h_r;
        _Float16* h_w;
        if (IS_ENC) {
            h_r = slots + (size_t)(10 + (t & 1)) * NBHD;
            h_w = slots + (size_t)(10 + ((t + 1) & 1)) * NBHD;
        } else {
            h_r = slots + (size_t)((t == 0) ? 10 : ((t - 1) % 10)) * NBHD;
            h_w = slots + (size_t)(t % 10) * NBHD;
        }

        // ---- wait: all 32 same-chain blocks finished step t-1 (first step
        // of a launch needs no wait: previous launch ordered by the stream).
        if (s > 0) {
            if (tid == 0) {
                const unsigned int* f =
                    cnt + (size_t)((IS_ENC ? t : 32 + t) - 1) * 32 + mt;
                while (__hip_atomic_load(f, __ATOMIC_RELAXED,
                                         __HIP_MEMORY_SCOPE_AGENT) < 32u)
                    __builtin_amdgcn_s_sleep(1);
            }
            __syncthreads();
            asm volatile("" ::: "memory");   // keep h loads below the spin
        }

        fx4 acc[2][4];
        #pragma unroll
        for (int i = 0; i < 2; i++)
            #pragma unroll
            for (int jj = 0; jj < 4; jj++)
                acc[i][jj] = fx4{0.f, 0.f, 0.f, 0.f};

        if (!(IS_ENC && t == 0)) {           // enc s=0: h==0, skip GEMM
            for (int k0 = 0; k0 < HD; k0 += 64) {
                const size_t kt = (size_t)(k0 >> 4) * (NB * 16);
                __syncthreads();             // prev iter's LDS reads done
                // A: sc0 loads (bypass L1, hit shared intra-XCD L2 = fresh)
                intx4 av[4];
                #pragma unroll
                for (int i = 0; i < 4; i++) {
                    unsigned long long ad =
                        (unsigned long long)(uintptr_t)(h_r + kt + aoff[i]);
                    asm volatile("global_load_dwordx4 %0, %1, off sc0"
                                 : "=v"(av[i]) : "v"(ad) : "memory");
                }
                #pragma unroll
                for (int i = 0; i < 2; i++)  // B: immutable, normal DMA path
                    gl2lds16(bg[i] + k0, &lsB[(wid * 16 + i * 8) * 64]);
                asm volatile("s_waitcnt vmcnt(0)" ::: "memory");
                __builtin_amdgcn_sched_barrier(0);
                #pragma unroll
                for (int i = 0; i < 4; i++)
                    *(intx4*)&lsA[(wid * 32 + i * 8) * 64 + lane * 8] = av[i];
                __syncthreads();
                #pragma unroll
                for (int kk = 0; kk < 64; kk += 32) {
                    const int kc = (kk >> 3) + quad;
                    half8 af[2], bf[4];
                    #pragma unroll
                    for (int mf = 0; mf < 2; mf++) {
                        int ar = wm + mf * 16 + l15;
                        int sw = ((kc ^ (ar & 7)) << 3);
                        af[mf] = *(const half8*)&lsA[ar * 64 + sw];
                    }
                    #pragma unroll
                    for (int g = 0; g < 4; g++) {
                        int br = g * 16 + l15;
                        int sw = ((kc ^ (br & 7)) << 3);
                        bf[g] = *(const half8*)&lsB[br * 64 + sw];
                    }
                    #pragma unroll
                    for (int mf = 0; mf < 2; mf++)
                        #pragma unroll
                        for (int g = 0; g < 4; g++)
                            acc[mf][g] = __builtin_amdgcn_mfma_f32_16x16x32_f16(
                                af[mf], bf[g], acc[mf][g], 0, 0, 0);
                }
            }
        }

        // ---- fused cell epilogue (identical math to R10), h via LDS bounce
        __syncthreads();                      // lsB frag reads done
        _Float16* htile = lsB;                // [128][16]
        #pragma unroll
        for (int mf = 0; mf < 2; mf++) {
            #pragma unroll
            for (int rr = 0; rr < 4; rr++) {
                const int lrow = wm + mf * 16 + quad * 4 + rr;
                const int row = m0 + lrow;
                int tok;
                if (IS_ENC) tok = seq[row * SSRC + t];
                else        tok = (t == 0) ? 1 : seq[row * STGT + t - 1]; // SOS=1
                const float* xp = proj + (size_t)tok * G4 + hcol;
                float gi = acc[mf][0][rr] + xp[0];
                float gf = acc[mf][1][rr] + xp[HD];
                float gg = acc[mf][2][rr] + xp[2 * HD];
                float go = acc[mf][3][rr] + xp[3 * HD];
                float ii = sigf(gi), ff = sigf(gf), oo = sigf(go);
                float g2 = tanhfast(gg);
                float cold = creg[mf][rr];
                float c2 = ff * cold + ii * g2;
                _Float16 h2 = (_Float16)(oo * tanhfast(c2));
                if (IS_ENC && t >= lenreg[mf][rr]) {   // pack_padded semantics
                    c2 = cold;
                    h2 = hreg[mf][rr];                  // exact fp16 carry
                }
                creg[mf][rr] = c2;
                if (IS_ENC) hreg[mf][rr] = h2;
                htile[lrow * 16 + l15] = h2;
            }
        }
        __syncthreads();
        {   // coalesced write-out: 16B/thread, normal stores (write-through
            // to this XCD's L2; consumers are same-XCD)
            const int lrow = tid >> 1, cof = (tid & 1) * 8;
            intx4 v = *(const intx4*)&htile[lrow * 16 + cof];
            *(intx4*)(h_w + ((size_t)ct * NB + (m0 + lrow)) * 16 + cof) = v;
        }
        // per-thread drain: my stores are in L2 before I arrive
        asm volatile("s_waitcnt vmcnt(0)" ::: "memory");
        // ---- arrive: barrier, then one agent-atomic signal per block
        if (s < nsteps - 1) {
            __syncthreads();
            if (tid == 0)
                __hip_atomic_fetch_add(
                    cnt + (size_t)(IS_ENC ? t : 32 + t) * 32 + mt, 1u,
                    __ATOMIC_RELAXED, __HIP_MEMORY_SCOPE_AGENT);
        }
    }

    #pragma unroll
    for (int mf = 0; mf < 2; mf++)
        #pragma unroll
        for (int rr = 0; rr < 4; rr++) {
            int row = m0 + wm + mf * 16 + quad * 4 + rr;
            c_state[(size_t)row * HD + hcol] = creg[mf][rr];
        }
}

// Batched outproj: 256 blocks = (8 t) x (32 m-tiles), each 128x128x512.
// A-addressing matches the [ctile][row][16] slot layout.
__global__ __launch_bounds__(256, 2) void outproj_batch(
    const _Float16* __restrict__ h_slots, int t0,
    const _Float16* __restrict__ Wo, const float* __restrict__ bout,
    float* __restrict__ out)
{
    __shared__ __align__(16) _Float16 lsA[128 * 64];
    __shared__ __align__(16) _Float16 lsB[128 * 64];

    const int tid = threadIdx.x;
    const int lane = tid & 63;
    const int wid  = tid >> 6;
    const int srow = lane >> 3;
    const int skc  = (((lane & 7) ^ srow)) << 3;
    const int wm    = (wid >> 1) * 64;
    const int wncol = wid & 1;
    const int quad  = lane >> 4;
    const int l15   = lane & 15;
    const int bsw   = (l15 & 7);

    const int t  = t0 + ((int)blockIdx.x >> 5);
    const int m0 = ((int)blockIdx.x & 31) * 128;
    const _Float16* h_r = h_slots + (size_t)(t % 10) * NBHD;

    int aoff[4];
    const _Float16* bg[4];
    #pragma unroll
    for (int i = 0; i < 4; i++) {
        int lr = wid * 32 + i * 8 + srow;
        aoff[i] = ((skc >> 4) * NB + (m0 + lr)) * 16 + (skc & 8);
        bg[i] = Wo + (size_t)lr * HD + skc;   // Wout row = v
    }

    fx4 acc[4][4];
    #pragma unroll
    for (int i = 0; i < 4; i++)
        #pragma unroll
        for (int jj = 0; jj < 4; jj++)
            acc[i][jj] = fx4{0.f, 0.f, 0.f, 0.f};

    for (int k0 = 0; k0 < HD; k0 += 64) {
        const size_t kt = (size_t)(k0 >> 4) * (NB * 16);
        __syncthreads();
        #pragma unroll
        for (int i = 0; i < 4; i++) {
            int lb = (wid * 32 + i * 8) * 64;
            gl2lds16(h_r + kt + aoff[i], &lsA[lb]);
            gl2lds16(bg[i] + k0, &lsB[lb]);
        }
        __syncthreads();
        #pragma unroll
        for (int kk = 0; kk < 64; kk += 32) {
            const int kc = (kk >> 3) + quad;
            const int sw = ((kc ^ bsw) << 3);
            half8 af[4], bf[4];
            #pragma unroll
            for (int mt = 0; mt < 4; mt++)
                af[mt] = *(const half8*)&lsA[(wm + mt * 16 + l15) * 64 + sw];
            #pragma unroll
            for (int nt = 0; nt < 4; nt++)
                bf[nt] = *(const half8*)&lsB[(wncol * 64 + nt * 16 + l15) * 64 + sw];
            #pragma unroll
            for (int mt = 0; mt < 4; mt++)
                #pragma unroll
                for (int nt = 0; nt < 4; nt++)
                    acc[mt][nt] = __builtin_amdgcn_mfma_f32_16x16x32_f16(af[mt], bf[nt], acc[mt][nt], 0, 0, 0);
        }
    }

    #pragma unroll
    for (int mt = 0; mt < 4; mt++)
        #pragma unroll
        for (int nt = 0; nt < 4; nt++) {
            int v = wncol * 64 + nt * 16 + l15;
            float bo = bout[v];
            #pragma unroll
            for (int rr = 0; rr < 4; rr++) {
                int row = m0 + wm + mt * 16 + quad * 4 + rr;
                out[((size_t)row * STGT + t) * NVTGT + v] = acc[mt][nt][rr] + bo;
            }
        }
}

extern "C" void kernel_launch(void* const* d_in, const int* in_sizes, int n_in,
                              void* d_out, int out_size, void* d_ws, size_t ws_size,
                              hipStream_t stream) {
    (void)in_sizes; (void)n_in; (void)out_size; (void)ws_size;
    const int* src_seq = (const int*)d_in[0];
    const int* src_len = (const int*)d_in[1];
    const int* tgt_seq = (const int*)d_in[2];
    const float* emb_src = (const float*)d_in[3];
    const float* eWih = (const float*)d_in[4];
    const float* eWhh = (const float*)d_in[5];
    const float* ebih = (const float*)d_in[6];
    const float* ebhh = (const float*)d_in[7];
    const float* emb_tgt = (const float*)d_in[8];
    const float* dWih = (const float*)d_in[9];
    const float* dWhh = (const float*)d_in[10];
    const float* dbih = (const float*)d_in[11];
    const float* dbhh = (const float*)d_in[12];
    const float* Wout = (const float*)d_in[13];
    const float* bout = (const float*)d_in[14];
    float* out = (float*)d_out;

    char* ws = (char*)d_ws;
    size_t off = 0;
    auto carve = [&](size_t bytes) { void* p = ws + off; off += (bytes + 255) & ~(size_t)255; return p; };
    float* proj_src = (float*)carve((size_t)NVSRC * G4 * 4);
    float* proj_tgt = (float*)carve((size_t)NVTGT * G4 * 4);
    float* c_state  = (float*)carve(NBHD * 4);
    _Float16* slots = (_Float16*)carve((size_t)12 * NBHD * 2);   // 48 MB
    _Float16* eW_h  = (_Float16*)carve((size_t)G4 * HD * 2);
    _Float16* dW_h  = (_Float16*)carve((size_t)G4 * HD * 2);
    _Float16* Wo_h  = (_Float16*)carve((size_t)NVTGT * HD * 2);
    unsigned int* cnt = (unsigned int*)carve((size_t)64 * 32 * 4); // arrivals
    // WT buffers alias decoder slot 0 (first written at decoder step 0,
    // long after tables are built). 1 MB each, slot is 4 MB.
    float* WT_e = (float*)(slots);
    float* WT_d = (float*)((char*)slots + (size_t)ED * G4 * 4);

    hipMemsetAsync(c_state, 0, NBHD * 4, stream);
    hipMemsetAsync(cnt, 0, (size_t)64 * 32 * 4, stream);

    convert_half<<<dim3(G4 * HD / 256), dim3(256), 0, stream>>>(eWhh, G4 * HD, eW_h);
    convert_half<<<dim3(G4 * HD / 256), dim3(256), 0, stream>>>(dWhh, G4 * HD, dW_h);
    convert_half<<<dim3(NVTGT * HD / 256), dim3(256), 0, stream>>>(Wout, NVTGT * HD, Wo_h);
    transpose_f32<<<dim3((G4 / 32) * (ED / 32)), dim3(256), 0, stream>>>(eWih, WT_e, G4, ED, G4 / 32);
    transpose_f32<<<dim3((G4 / 32) * (ED / 32)), dim3(256), 0, stream>>>(dWih, WT_d, G4, ED, G4 / 32);
    build_tables3<<<dim3((NVSRC / 8) * 8), dim3(256), 0, stream>>>(emb_src, WT_e, ebih, ebhh, proj_src);
    build_tables3<<<dim3((NVTGT / 8) * 8), dim3(256), 0, stream>>>(emb_tgt, WT_d, dbih, dbhh, proj_tgt);

    // encoder: one persistent launch, 32 steps (slots 10/11 alternate)
    lstm_persist<1><<<dim3(1024), dim3(256), 0, stream>>>(
        slots, c_state, proj_src, src_seq, src_len, eW_h, cnt, 0, 32);
    // decoder: 4 persistent launches of 8 steps (ring-10), outproj between
    for (int k = 0; k < 4; k++) {
        lstm_persist<0><<<dim3(1024), dim3(256), 0, stream>>>(
            slots, c_state, proj_tgt, tgt_seq, nullptr, dW_h, cnt, k * 8, 8);
        outproj_batch<<<dim3(256), dim3(256), 0, stream>>>(
            slots, k * 8, Wo_h, bout, out);
    }
}

// Round 3
// 1595.758 us; speedup vs baseline: 3.9859x; 2.2324x over previous
//
#include <hip/hip_runtime.h>
#include <hip/hip_bf16.h>
#include <hip/hip_fp16.h>
#include <stdint.h>

// Seq2Seq LSTM: B=4096, H=512, E=128, 32 enc + 32 dec steps, V_tgt=128.
// Round 13: REVERT to R10 structure (per-step launches, proven 1558 us) +
// counted-vmcnt double-buffered K-pipeline in lstm_step (T3+T4):
//  - A tiles double-buffered (2x16KB), B single (8KB) => 40KB LDS, still
//    4 blocks/CU so all 1024 blocks co-resident per launch.
//  - raw s_barrier (NOT __syncthreads: compiler emits vmcnt(0) drain) +
//    steady-state s_waitcnt vmcnt(4): next A-tile's 4 loads stay in flight
//    across both barriers; B prefetched 1 iter ahead, ordered before the
//    A-stage so vmcnt(4) covers it.
//  - s_setprio(1) around the MFMA cluster.
// Per-cell math/order identical to R10 -> absmax bitwise identical.
// R11/R12 persistent-chain experiments removed (coherence data-path cost
// dominated: agent atomics / L2 thrash, MfmaUtil 3-6%).

#define NB     4096
#define SSRC   32
#define STGT   32
#define NVSRC  96
#define NVTGT  128
#define ED     128
#define HD     512
#define G4     2048   // 4*HD
#define NBHD   ((size_t)NB * HD)

typedef __attribute__((ext_vector_type(8))) _Float16 half8;
typedef __attribute__((ext_vector_type(4))) float fx4;

#define AS_G __attribute__((address_space(1)))
#define AS_L __attribute__((address_space(3)))

__device__ __forceinline__ void gl2lds16(const void* g, void* l) {
    // async global->LDS DMA, 16B/lane; LDS dest = wave-uniform base + lane*16
    __builtin_amdgcn_global_load_lds((const AS_G uint32_t*)g, (AS_L uint32_t*)l, 16, 0, 0);
}

__device__ __forceinline__ float sigf(float x) { return 1.0f / (1.0f + __expf(-x)); }
__device__ __forceinline__ float tanhfast(float x) { return 1.0f - 2.0f / (__expf(2.0f * x) + 1.0f); }

__global__ void convert_half(const float* __restrict__ src, int n, _Float16* __restrict__ dst) {
    int i = blockIdx.x * 256 + threadIdx.x;
    if (i < n) dst[i] = (_Float16)src[i];
}

// 32x32 LDS-tiled transpose: outT[c][r] = in[r][c]; both sides coalesced.
__global__ __launch_bounds__(256) void transpose_f32(
    const float* __restrict__ in, float* __restrict__ outT, int R, int C, int rtiles)
{
    __shared__ float ls[32][33];
    const int bx = (int)blockIdx.x % rtiles;     // r-tile
    const int by = (int)blockIdx.x / rtiles;     // c-tile
    const int tx = threadIdx.x & 31, ty = threadIdx.x >> 5;   // ty 0..7
    #pragma unroll
    for (int i = 0; i < 4; i++) {
        int rr = ty + i * 8;
        ls[rr][tx] = in[(size_t)(bx * 32 + rr) * C + by * 32 + tx];
    }
    __syncthreads();
    #pragma unroll
    for (int i = 0; i < 4; i++) {
        int rr = ty + i * 8;
        outT[(size_t)(by * 32 + rr) * R + bx * 32 + tx] = ls[tx][rr];
    }
}

// proj[v][g] = emb[v,:]·Wih[g,:] + bih[g] + bhh[g], using WT[e][g] (coalesced).
__global__ __launch_bounds__(256) void build_tables3(
    const float* __restrict__ emb, const float* __restrict__ WT,
    const float* __restrict__ bih, const float* __restrict__ bhh,
    float* __restrict__ proj)
{
    __shared__ float embL[8][ED];
    const int gc = (int)blockIdx.x & 7;
    const int vc = (int)blockIdx.x >> 3;
    const int g  = gc * 256 + threadIdx.x;
    for (int i = threadIdx.x; i < 8 * ED; i += 256)
        embL[i >> 7][i & (ED - 1)] = emb[(size_t)(vc * 8 + (i >> 7)) * ED + (i & (ED - 1))];
    __syncthreads();
    float acc[8] = {0, 0, 0, 0, 0, 0, 0, 0};
    for (int e = 0; e < ED; e++) {
        float w = WT[(size_t)e * G4 + g];
        #pragma unroll
        for (int v = 0; v < 8; v++) acc[v] += embL[v][e] * w;
    }
    float bb = bih[g] + bhh[g];
    #pragma unroll
    for (int v = 0; v < 8; v++)
        proj[(size_t)(vc * 8 + v) * G4 + g] = acc[v] + bb;
}

// Gate GEMM, 128m x 64n (4 gates x 16 hcols) per block + fused cell epilogue.
// 1024 blocks = 4 blocks/CU (16 waves/CU). Wave = 32m x 64n: 2 m-frags x
// 4 n-frags (n-frag == gate), so each lane owns all 4 gates per (row,hcol).
// K-loop: A double-buffered + counted vmcnt pipeline (see header comment).
__global__ __launch_bounds__(256, 4) void lstm_step(
    const _Float16* __restrict__ h_r, _Float16* __restrict__ h_w,
    float* __restrict__ c_state,
    const float* __restrict__ proj,
    const int* __restrict__ seq, const int* __restrict__ lens,
    const _Float16* __restrict__ W,
    int t, int is_enc, int skip_gemm)
{
    __shared__ __align__(16) _Float16 lsA[2][128 * 64];   // 32 KB (dbuf)
    __shared__ __align__(16) _Float16 lsB[64 * 64];       // 8 KB

    const int tid = threadIdx.x;
    const int lane = tid & 63;
    const int wid  = tid >> 6;
    const int srow = lane >> 3;                    // staging row-in-group
    const int skc  = (((lane & 7) ^ srow)) << 3;   // XOR-swizzled k-chunk
    const int wm   = wid * 32;                     // wave m-offset (0..96)
    const int quad = lane >> 4;
    const int l15  = lane & 15;

    // XCD swizzle: per-XCD ws = 16 m-tiles (2 MB A) + 8 hcol-tiles (0.5 MB B)
    const int x = (int)blockIdx.x & 7, j = (int)blockIdx.x >> 3;
    const int m0 = ((x & 1) * 16 + (j & 15)) * 128;    // batch tile (32 total)
    const int c0 = ((x >> 1) * 8 + (j >> 4)) * 16;     // hcol tile (32 total)

    const _Float16 *ag[4], *bg[2];
    #pragma unroll
    for (int i = 0; i < 4; i++) {
        int lr = wid * 32 + i * 8 + srow;              // local A row 0..127
        ag[i] = h_r + (size_t)(m0 + lr) * HD + skc;
    }
    #pragma unroll
    for (int i = 0; i < 2; i++) {
        int lr = wid * 16 + i * 8 + srow;              // local B row 0..63
        // lr -> (gate = lr>>4, tcol = lr&15)
        int wr = (lr >> 4) * HD + c0 + (lr & 15);
        bg[i] = W + (size_t)wr * HD + skc;
    }

    fx4 acc[2][4];
    #pragma unroll
    for (int i = 0; i < 2; i++)
        #pragma unroll
        for (int jj = 0; jj < 4; jj++)
            acc[i][jj] = fx4{0.f, 0.f, 0.f, 0.f};

    if (!skip_gemm) {
        // ---- prologue: B(0), A(buf0,tile0), A(buf1,tile1)   [10 loads/wave]
        #pragma unroll
        for (int i = 0; i < 2; i++)
            gl2lds16(bg[i], &lsB[(wid * 16 + i * 8) * 64]);
        #pragma unroll
        for (int i = 0; i < 4; i++)
            gl2lds16(ag[i], &lsA[0][(wid * 32 + i * 8) * 64]);
        #pragma unroll
        for (int i = 0; i < 4; i++)
            gl2lds16(ag[i] + 64, &lsA[1][(wid * 32 + i * 8) * 64]);

        // ---- 8 k-tiles, steady-state vmcnt(4): next A-tile (4 loads) stays
        // in flight across both barriers; B(it) + A(it) proven landed.
        #pragma unroll
        for (int it = 0; it < 8; it++) {
            if (it < 7) asm volatile("s_waitcnt vmcnt(4)" ::: "memory");
            else        asm volatile("s_waitcnt vmcnt(0)" ::: "memory");
            __builtin_amdgcn_s_barrier();
            __builtin_amdgcn_sched_barrier(0);
            const _Float16* la = lsA[it & 1];
            __builtin_amdgcn_s_setprio(1);
            #pragma unroll
            for (int kk = 0; kk < 64; kk += 32) {
                const int kc = (kk >> 3) + quad;
                half8 af[2], bf[4];
                #pragma unroll
                for (int mf = 0; mf < 2; mf++) {
                    int ar = wm + mf * 16 + l15;
                    int sw = ((kc ^ (ar & 7)) << 3);
                    af[mf] = *(const half8*)&la[ar * 64 + sw];
                }
                #pragma unroll
                for (int g = 0; g < 4; g++) {
                    int br = g * 16 + l15;
                    int sw = ((kc ^ (br & 7)) << 3);
                    bf[g] = *(const half8*)&lsB[br * 64 + sw];
                }
                #pragma unroll
                for (int mf = 0; mf < 2; mf++)
                    #pragma unroll
                    for (int g = 0; g < 4; g++)
                        acc[mf][g] = __builtin_amdgcn_mfma_f32_16x16x32_f16(
                            af[mf], bf[g], acc[mf][g], 0, 0, 0);
            }
            __builtin_amdgcn_s_setprio(0);
            if (it < 7) {
                __builtin_amdgcn_sched_barrier(0);
                __builtin_amdgcn_s_barrier();     // all waves done reading
                // B for next tile FIRST (so vmcnt(4) at next top covers it),
                // then A for tile it+2 into the buffer just freed.
                #pragma unroll
                for (int i = 0; i < 2; i++)
                    gl2lds16(bg[i] + (it + 1) * 64, &lsB[(wid * 16 + i * 8) * 64]);
                if (it + 2 < 8) {
                    #pragma unroll
                    for (int i = 0; i < 4; i++)
                        gl2lds16(ag[i] + (it + 2) * 64, &lsA[it & 1][(wid * 32 + i * 8) * 64]);
                }
            }
        }
    }

    // fused cell epilogue: acc[mf][gate][r] — all 4 gates per (row,hcol)
    const int hcol = c0 + l15;
    #pragma unroll
    for (int mf = 0; mf < 2; mf++) {
        #pragma unroll
        for (int r = 0; r < 4; r++) {
            int row = m0 + wm + mf * 16 + quad * 4 + r;
            int tok = is_enc ? seq[row * SSRC + t]
                             : (t == 0 ? 1 : seq[row * STGT + t - 1]);  // SOS=1
            const float* xp = proj + (size_t)tok * G4 + hcol;
            float gi = acc[mf][0][r] + xp[0];
            float gf = acc[mf][1][r] + xp[HD];
            float gg = acc[mf][2][r] + xp[2 * HD];
            float go = acc[mf][3][r] + xp[3 * HD];
            float ii = sigf(gi), ff = sigf(gf), oo = sigf(go);
            float g2 = tanhfast(gg);
            size_t off = (size_t)row * HD + hcol;
            float cold = c_state[off];
            float c2 = ff * cold + ii * g2;
            float h2 = oo * tanhfast(c2);
            if (is_enc && t >= lens[row]) {   // pack_padded semantics
                c2 = cold;
                h2 = (float)h_r[off];          // exact fp16 carry
            }
            c_state[off] = c2;
            h_w[off] = (_Float16)h2;
        }
    }
}

// Batched outproj: 256 blocks = (8 t) x (32 m-tiles), each 128x128x512.
__global__ __launch_bounds__(256, 2) void outproj_batch(
    const _Float16* __restrict__ h_slots, int t0,
    const _Float16* __restrict__ Wo, const float* __restrict__ bout,
    float* __restrict__ out)
{
    __shared__ __align__(16) _Float16 lsA[128 * 64];
    __shared__ __align__(16) _Float16 lsB[128 * 64];

    const int tid = threadIdx.x;
    const int lane = tid & 63;
    const int wid  = tid >> 6;
    const int srow = lane >> 3;
    const int skc  = (((lane & 7) ^ srow)) << 3;
    const int wm    = (wid >> 1) * 64;
    const int wncol = wid & 1;
    const int quad  = lane >> 4;
    const int l15   = lane & 15;
    const int bsw   = (l15 & 7);

    const int t  = t0 + ((int)blockIdx.x >> 5);
    const int m0 = ((int)blockIdx.x & 31) * 128;
    const _Float16* h_r = h_slots + (size_t)(t % 10) * NBHD;

    const _Float16 *ag[4], *bg[4];
    #pragma unroll
    for (int i = 0; i < 4; i++) {
        int lr = wid * 32 + i * 8 + srow;
        ag[i] = h_r + (size_t)(m0 + lr) * HD + skc;
        bg[i] = Wo + (size_t)lr * HD + skc;   // Wout row = v
    }

    fx4 acc[4][4];
    #pragma unroll
    for (int i = 0; i < 4; i++)
        #pragma unroll
        for (int jj = 0; jj < 4; jj++)
            acc[i][jj] = fx4{0.f, 0.f, 0.f, 0.f};

    for (int k0 = 0; k0 < HD; k0 += 64) {
        __syncthreads();
        #pragma unroll
        for (int i = 0; i < 4; i++) {
            int lb = (wid * 32 + i * 8) * 64;
            gl2lds16(ag[i] + k0, &lsA[lb]);
            gl2lds16(bg[i] + k0, &lsB[lb]);
        }
        __syncthreads();
        #pragma unroll
        for (int kk = 0; kk < 64; kk += 32) {
            const int kc = (kk >> 3) + quad;
            const int sw = ((kc ^ bsw) << 3);
            half8 af[4], bf[4];
            #pragma unroll
            for (int mt = 0; mt < 4; mt++)
                af[mt] = *(const half8*)&lsA[(wm + mt * 16 + l15) * 64 + sw];
            #pragma unroll
            for (int nt = 0; nt < 4; nt++)
                bf[nt] = *(const half8*)&lsB[(wncol * 64 + nt * 16 + l15) * 64 + sw];
            #pragma unroll
            for (int mt = 0; mt < 4; mt++)
                #pragma unroll
                for (int nt = 0; nt < 4; nt++)
                    acc[mt][nt] = __builtin_amdgcn_mfma_f32_16x16x32_f16(af[mt], bf[nt], acc[mt][nt], 0, 0, 0);
        }
    }

    #pragma unroll
    for (int mt = 0; mt < 4; mt++)
        #pragma unroll
        for (int nt = 0; nt < 4; nt++) {
            int v = wncol * 64 + nt * 16 + l15;
            float bo = bout[v];
            #pragma unroll
            for (int r = 0; r < 4; r++) {
                int row = m0 + wm + mt * 16 + quad * 4 + r;
                out[((size_t)row * STGT + t) * NVTGT + v] = acc[mt][nt][r] + bo;
            }
        }
}

extern "C" void kernel_launch(void* const* d_in, const int* in_sizes, int n_in,
                              void* d_out, int out_size, void* d_ws, size_t ws_size,
                              hipStream_t stream) {
    (void)in_sizes; (void)n_in; (void)out_size; (void)ws_size;
    const int* src_seq = (const int*)d_in[0];
    const int* src_len = (const int*)d_in[1];
    const int* tgt_seq = (const int*)d_in[2];
    const float* emb_src = (const float*)d_in[3];
    const float* eWih = (const float*)d_in[4];
    const float* eWhh = (const float*)d_in[5];
    const float* ebih = (const float*)d_in[6];
    const float* ebhh = (const float*)d_in[7];
    const float* emb_tgt = (const float*)d_in[8];
    const float* dWih = (const float*)d_in[9];
    const float* dWhh = (const float*)d_in[10];
    const float* dbih = (const float*)d_in[11];
    const float* dbhh = (const float*)d_in[12];
    const float* Wout = (const float*)d_in[13];
    const float* bout = (const float*)d_in[14];
    float* out = (float*)d_out;

    char* ws = (char*)d_ws;
    size_t off = 0;
    auto carve = [&](size_t bytes) { void* p = ws + off; off += (bytes + 255) & ~(size_t)255; return p; };
    float* proj_src = (float*)carve((size_t)NVSRC * G4 * 4);
    float* proj_tgt = (float*)carve((size_t)NVTGT * G4 * 4);
    float* c_state  = (float*)carve(NBHD * 4);
    _Float16* slots = (_Float16*)carve((size_t)12 * NBHD * 2);   // 48 MB
    _Float16* eW_h  = (_Float16*)carve((size_t)G4 * HD * 2);
    _Float16* dW_h  = (_Float16*)carve((size_t)G4 * HD * 2);
    _Float16* Wo_h  = (_Float16*)carve((size_t)NVTGT * HD * 2);
    // WT buffers alias decoder slot 0 (first written at decoder step 0,
    // long after tables are built). 1 MB each, slot is 4 MB.
    float* WT_e = (float*)(slots);
    float* WT_d = (float*)((char*)slots + (size_t)ED * G4 * 4);
    auto slot = [&](int i) { return slots + (size_t)i * NBHD; };

    hipMemsetAsync(c_state, 0, NBHD * 4, stream);
    hipMemsetAsync(slot(10), 0, NBHD * 2, stream);   // initial h = 0

    convert_half<<<dim3(G4 * HD / 256), dim3(256), 0, stream>>>(eWhh, G4 * HD, eW_h);
    convert_half<<<dim3(G4 * HD / 256), dim3(256), 0, stream>>>(dWhh, G4 * HD, dW_h);
    convert_half<<<dim3(NVTGT * HD / 256), dim3(256), 0, stream>>>(Wout, NVTGT * HD, Wo_h);
    transpose_f32<<<dim3((G4 / 32) * (ED / 32)), dim3(256), 0, stream>>>(eWih, WT_e, G4, ED, G4 / 32);
    transpose_f32<<<dim3((G4 / 32) * (ED / 32)), dim3(256), 0, stream>>>(dWih, WT_d, G4, ED, G4 / 32);
    build_tables3<<<dim3((NVSRC / 8) * 8), dim3(256), 0, stream>>>(emb_src, WT_e, ebih, ebhh, proj_src);
    build_tables3<<<dim3((NVTGT / 8) * 8), dim3(256), 0, stream>>>(emb_tgt, WT_d, dbih, dbhh, proj_tgt);

    // encoder: slots 10/11 alternate; s=0 skips GEMM (h==0)
    for (int s = 0; s < 32; s++) {
        lstm_step<<<dim3(1024), dim3(256), 0, stream>>>(
            slot(10 + (s & 1)), slot(10 + ((s + 1) & 1)), c_state,
            proj_src, src_seq, src_len, eW_h, s, 1, (s == 0));
    }
    // decoder: 10-slot ring (slot = t mod 10); outproj batches of 8
    for (int t = 0; t < 32; t++) {
        const _Float16* hr = (t == 0) ? slot(10) : slot((t - 1) % 10);
        lstm_step<<<dim3(1024), dim3(256), 0, stream>>>(
            hr, slot(t % 10), c_state,
            proj_tgt, tgt_seq, nullptr, dW_h, t, 0, 0);
        if ((t & 7) == 7) {
            outproj_batch<<<dim3(256), dim3(256), 0, stream>>>(
                slots, t - 7, Wo_h, bout, out);
        }
    }
}